// Round 4
// baseline (685.367 us; speedup 1.0000x reference)
//
#include <hip/hip_runtime.h>
#include <hip/hip_bf16.h>
#include <math.h>

#define N_NODES 50000
#define DEG 16
#define FIN 256
#define FOUT 128
#define HID 128
#define FG 512            // 4*HID
#define NEDGE (N_NODES*DEG)
#define NCHUNK (N_NODES/16)   // 3125 exactly
#define NPAIR ((NCHUNK+1)/2)  // 1563

typedef __bf16 bf16x8 __attribute__((ext_vector_type(8)));
typedef float  f32x4  __attribute__((ext_vector_type(4)));

// ---------------- helpers ----------------
static __device__ __forceinline__ float u2f(unsigned int u){ union {unsigned int u; float f;} v; v.u=u; return v.f; }
static __device__ __forceinline__ unsigned int f2u(float f){ union {float f; unsigned int u;} v; v.f=f; return v.u; }
static __device__ __forceinline__ unsigned short f2bfu(float f){  // RNE float->bf16 bits
  unsigned int u = f2u(f);
  unsigned int r = u + 0x7fffu + ((u >> 16) & 1u);
  return (unsigned short)(r >> 16);
}
static __device__ __forceinline__ float bflo(unsigned int u){ return u2f(u << 16); }
static __device__ __forceinline__ float bfhi(unsigned int u){ return u2f(u & 0xffff0000u); }
static __device__ __forceinline__ float sigm(float x){ return 1.f/(1.f + __expf(-x)); }
static __device__ __forceinline__ float tanhx(float x){ return 1.f - 2.f/(__expf(2.f*x) + 1.f); }

union FU { bf16x8 bf; unsigned short us[8]; uint4 u4; };

// ---------------- K0: init global-max key ----------------
__global__ void k0_init(unsigned int* __restrict__ gmax_key){
  if (threadIdx.x == 0) *gmax_key = 0u;
}

// ---------------- KA: x -> bf16 hi/lo planes ----------------
__global__ __launch_bounds__(256) void k_cvt(
    const float* __restrict__ x, unsigned short* __restrict__ xh, unsigned short* __restrict__ xl)
{
  const int idx = blockIdx.x*256 + threadIdx.x;     // float4 granules
  if (idx >= (N_NODES*FIN)/4) return;
  const float4 v = ((const float4*)x)[idx];
  ushort4 h, l;
  h.x = f2bfu(v.x); l.x = f2bfu(v.x - u2f((unsigned)h.x << 16));
  h.y = f2bfu(v.y); l.y = f2bfu(v.y - u2f((unsigned)h.y << 16));
  h.z = f2bfu(v.z); l.z = f2bfu(v.z - u2f((unsigned)h.z << 16));
  h.w = f2bfu(v.w); l.w = f2bfu(v.w - u2f((unsigned)h.w << 16));
  ((ushort4*)xh)[idx] = h;
  ((ushort4*)xl)[idx] = l;
}

// ---------------- KW: weight converts + v = W^T a (double) + w_hh B-frag pack ----------------
// blocks 0..255: Wcomb row n ([Wp;Ws], 256 cols) -> Wch/Wcl
// blocks 256..511: wih rows (b-256)*2, +1 -> wihh/wihl
// block 512: vsrc/vtrg[k] = sum_i a[i]*Wp[i,k] in double
// blocks 513..768: whh [512,128] -> Pw bf16 packed in MFMA B-fragment order:
//   Pw[((g*4+kt)*128 + fcol)*32 + q*8 + j] = bf16(whh[(g*128+fcol)*128 + kt*32+q*8+j])
__global__ __launch_bounds__(256) void k_w(
    const float* __restrict__ Wp, const float* __restrict__ Ws,
    const float* __restrict__ wih, const float* __restrict__ whh,
    const float* __restrict__ a_src, const float* __restrict__ a_trg,
    unsigned short* __restrict__ Wch, unsigned short* __restrict__ Wcl,
    unsigned short* __restrict__ wihh, unsigned short* __restrict__ wihl,
    unsigned short* __restrict__ Pw,
    double* __restrict__ vsrc, double* __restrict__ vtrg)
{
  const int b = blockIdx.x, tid = threadIdx.x;
  if (b < 256) {
    const float* src = (b < 128) ? (Wp + b*FIN) : (Ws + (b-128)*FIN);
    const float v = src[tid];
    const unsigned short h = f2bfu(v);
    Wch[b*FIN + tid] = h;
    Wcl[b*FIN + tid] = f2bfu(v - u2f((unsigned)h << 16));
  } else if (b < 512) {
    const int row = (b-256)*2 + (tid >> 7);
    const int k   = tid & 127;
    const float v = wih[row*HID + k];
    const unsigned short h = f2bfu(v);
    wihh[row*HID + k] = h;
    wihl[row*HID + k] = f2bfu(v - u2f((unsigned)h << 16));
  } else if (b == 512) {
    const int k = tid;
    double s1 = 0.0, s2 = 0.0;
    for (int i = 0; i < FOUT; ++i) {
      const double w = (double)Wp[i*FIN + k];
      s1 += (double)a_src[i] * w;
      s2 += (double)a_trg[i] * w;
    }
    vsrc[k] = s1; vtrg[k] = s2;
  } else {
    const int row = (b-513)*2 + (tid >> 7);   // 0..511 = g*128 + fcol
    const int k   = tid & 127;
    const int g = row >> 7, fc = row & 127;
    const int kt = k >> 5, qq = (k >> 3) & 3, j = k & 7;
    Pw[((g*4 + kt)*128 + fc)*32 + qq*8 + j] = f2bfu(whh[row*HID + k]);
  }
}

// ---------------- KS: s_src/s_trg = x @ v (double) ----------------
__global__ __launch_bounds__(256) void k_s(
    const float* __restrict__ x, const double* __restrict__ vsrc, const double* __restrict__ vtrg,
    double* __restrict__ ssrc, double* __restrict__ strg)
{
  const int n = blockIdx.x*256 + threadIdx.x;
  if (n >= N_NODES) return;
  double ss = 0.0, st = 0.0;
  for (int k = 0; k < FIN; k += 4) {
    const float4 xv = *(const float4*)&x[n*FIN + k];
    ss += xv.x*vsrc[k] + xv.y*vsrc[k+1] + xv.z*vsrc[k+2] + xv.w*vsrc[k+3];
    st += xv.x*vtrg[k] + xv.y*vtrg[k+1] + xv.z*vtrg[k+2] + xv.w*vtrg[k+3];
  }
  ssrc[n] = ss; strg[n] = st;
}

// ---------------- KG: split-bf16 MFMA GEMM, 128x64 tile ----------------
template<int KD, int MODE>
__global__ __launch_bounds__(256) void kgemm(
    const unsigned short* __restrict__ Ah_g, const unsigned short* __restrict__ Al_g,
    const unsigned short* __restrict__ Bh_g, const unsigned short* __restrict__ Bl_g,
    const float* __restrict__ bias, float* __restrict__ outf,
    unsigned short* __restrict__ o_h, unsigned short* __restrict__ o_l)
{
  __shared__ unsigned short At[2][128*64];
  __shared__ unsigned short Bt[2][64*64];
  const int tid = threadIdx.x;
  const int bm = blockIdx.x, bn = blockIdx.y;
  const int r0 = bm*128;
  const int wave = tid >> 6, lane = tid & 63, c = lane & 15, q = lane >> 4;
  const int srow = tid >> 3, sg = tid & 7;

  f32x4 acc[2][4];
  #pragma unroll
  for (int rt = 0; rt < 2; ++rt)
    #pragma unroll
    for (int ct = 0; ct < 4; ++ct) acc[rt][ct] = (f32x4){0.f,0.f,0.f,0.f};

  for (int kt = 0; kt < KD/64; ++kt) {
    const int k0 = kt*64;
    __syncthreads();
    #pragma unroll
    for (int rr = 0; rr < 4; ++rr) {
      const int row = rr*32 + srow;
      int grow = r0 + row; if (grow >= N_NODES) grow = N_NODES-1;
      const int ga = grow*KD + k0 + sg*8;
      const int la = row*64 + (((sg ^ (row & 7))) << 3);
      *(uint4*)&At[0][la] = *(const uint4*)&Ah_g[ga];
      *(uint4*)&At[1][la] = *(const uint4*)&Al_g[ga];
    }
    #pragma unroll
    for (int rr = 0; rr < 2; ++rr) {
      const int row = rr*32 + srow;
      int wr;
      if (MODE == 0) wr = bn*64 + row;
      else { const int j = bn*64 + row; wr = (j & 3)*HID + (j >> 2); }
      const int ga = wr*KD + k0 + sg*8;
      const int la = row*64 + (((sg ^ (row & 7))) << 3);
      *(uint4*)&Bt[0][la] = *(const uint4*)&Bh_g[ga];
      *(uint4*)&Bt[1][la] = *(const uint4*)&Bl_g[ga];
    }
    __syncthreads();

    #pragma unroll
    for (int s = 0; s < 2; ++s) {
      FU Af[2][2], Bf[4][2];
      #pragma unroll
      for (int rt = 0; rt < 2; ++rt) {
        const int row = wave*32 + rt*16 + c;
        const int ad = row*64 + (((((s<<2)+q) ^ (row & 7))) << 3);
        Af[rt][0].u4 = *(const uint4*)&At[0][ad];
        Af[rt][1].u4 = *(const uint4*)&At[1][ad];
      }
      #pragma unroll
      for (int ct = 0; ct < 4; ++ct) {
        const int row = ct*16 + c;
        const int ad = row*64 + (((((s<<2)+q) ^ (row & 7))) << 3);
        Bf[ct][0].u4 = *(const uint4*)&Bt[0][ad];
        Bf[ct][1].u4 = *(const uint4*)&Bt[1][ad];
      }
      #pragma unroll
      for (int rt = 0; rt < 2; ++rt)
        #pragma unroll
        for (int ct = 0; ct < 4; ++ct) {
          acc[rt][ct] = __builtin_amdgcn_mfma_f32_16x16x32_bf16(Af[rt][0].bf, Bf[ct][0].bf, acc[rt][ct], 0,0,0);
          acc[rt][ct] = __builtin_amdgcn_mfma_f32_16x16x32_bf16(Af[rt][1].bf, Bf[ct][0].bf, acc[rt][ct], 0,0,0);
          acc[rt][ct] = __builtin_amdgcn_mfma_f32_16x16x32_bf16(Af[rt][0].bf, Bf[ct][1].bf, acc[rt][ct], 0,0,0);
        }
    }
  }
  __syncthreads();

  if (MODE == 0 && bn >= 2) {
    #pragma unroll
    for (int ct = 0; ct < 4; ++ct) {
      const int col = bn*64 + ct*16 + c - 128;
      const float bv = bias[col];
      #pragma unroll
      for (int rt = 0; rt < 2; ++rt)
        #pragma unroll
        for (int i = 0; i < 4; ++i) {
          const int row = r0 + wave*32 + rt*16 + q*4 + i;
          if (row < N_NODES) outf[row*FOUT + col] = acc[rt][ct][i] + bv;
        }
    }
  } else {
    #pragma unroll
    for (int rt = 0; rt < 2; ++rt)
      #pragma unroll
      for (int ct = 0; ct < 4; ++ct)
        #pragma unroll
        for (int i = 0; i < 4; ++i) {
          const int lrow = wave*32 + rt*16 + q*4 + i;
          const int lcol = ct*16 + c;
          const float v = acc[rt][ct][i];
          const unsigned short h = f2bfu(v);
          At[0][lrow*64 + lcol] = h;
          if (MODE == 0) At[1][lrow*64 + lcol] = f2bfu(v - u2f((unsigned)h << 16));
        }
    __syncthreads();
    const int ncols = (MODE == 0) ? FOUT : FG;
    #pragma unroll
    for (int rr = 0; rr < 4; ++rr) {
      const int row = rr*32 + srow;
      const int grow = r0 + row;
      if (grow < N_NODES) {
        const int dst = grow*ncols + bn*64 + sg*8;
        *(uint4*)&o_h[dst] = *(const uint4*)&At[0][row*64 + sg*8];
        if (MODE == 0) *(uint4*)&o_l[dst] = *(const uint4*)&At[1][row*64 + sg*8];
      }
    }
  }
}

// ---------------- K3: edge scores (double) + global max ----------------
__global__ __launch_bounds__(256) void k3_scores(
    const double* __restrict__ ssrc, const double* __restrict__ strg,
    const int* __restrict__ esrc, const int* __restrict__ etrg,
    double* __restrict__ scod, unsigned int* __restrict__ gmax_key)
{
  const int n = blockIdx.x*256 + threadIdx.x;
  float lmax = -3.0e38f;
  if (n < N_NODES) {
    const double stn = strg[etrg[n*DEG]];
    #pragma unroll
    for (int j = 0; j < DEG; ++j) {
      const int e = n*DEG + j;
      double sc = ssrc[esrc[e]] + stn;
      sc = (sc > 0.0) ? sc : 0.2*sc;
      scod[e] = sc;
      lmax = fmaxf(lmax, (float)sc);
    }
  }
  #pragma unroll
  for (int off = 32; off > 0; off >>= 1)
    lmax = fmaxf(lmax, __shfl_down(lmax, off, 64));
  __shared__ float wmax[4];
  if ((threadIdx.x & 63) == 0) wmax[threadIdx.x >> 6] = lmax;
  __syncthreads();
  if (threadIdx.x == 0) {
    const float mv = fmaxf(fmaxf(wmax[0], wmax[1]), fmaxf(wmax[2], wmax[3]));
    const unsigned int u = f2u(mv);
    const unsigned int key = (u & 0x80000000u) ? ~u : (u | 0x80000000u);
    atomicMax(gmax_key, key);
  }
}

// ---------------- K4: softmax att + descending rank ----------------
__global__ __launch_bounds__(256) void k4_att(
    const double* __restrict__ scod, const int* __restrict__ esrc,
    const unsigned int* __restrict__ gmax_key,
    float* __restrict__ atts, int* __restrict__ srcs)
{
  const int n = blockIdx.x*256 + threadIdx.x;
  if (n >= N_NODES) return;
  const unsigned int key = *gmax_key;
  const unsigned int u = (key & 0x80000000u) ? (key ^ 0x80000000u) : ~key;
  const float gmax = u2f(u);

  double sc[DEG]; float av[DEG]; int si[DEG];
  float sum = 0.f;
  #pragma unroll
  for (int j = 0; j < DEG; ++j) {
    sc[j] = scod[n*DEG + j];
    av[j] = __expf((float)sc[j] - gmax);
    sum  += av[j];
    si[j] = esrc[n*DEG + j];
  }
  const float inv = 1.f/(sum + 1e-16f);
  #pragma unroll
  for (int j = 0; j < DEG; ++j) {
    int r = 0;
    #pragma unroll
    for (int k = 0; k < DEG; ++k)
      r += (sc[k] > sc[j]) || (sc[k] == sc[j] && k > j);
    atts[n*DEG + r] = av[j]*inv;
    srcs[n*DEG + r] = si[j];
  }
}

// ---------------- K5: MFMA 16-step LSTM, 2 chunks/block, B-frags resident ----------------
// __launch_bounds__(512,2): 256 VGPR/wave so the 64-reg B array stays resident
// (round-3's VGPR_Count=76 forced per-step rematerialization of B from global —
//  the hidden ~600 VALU insts/step). Pw = w_hh pre-packed in B-fragment order.
// Two chunks interleaved per block: 2x work between barriers at 1 block/CU.
__global__ __launch_bounds__(512, 2) void k5_lstm(
    const unsigned short* __restrict__ Gu, const unsigned short* __restrict__ Pw,
    const float* __restrict__ bih, const float* __restrict__ bhh,
    const float* __restrict__ atts, const int* __restrict__ srcs,
    float* __restrict__ out)
{
  __shared__ unsigned short hbuf[2][2][16*128];  // [chunk][buf][node*128 + swizzle]
  __shared__ float attb[2*256];
  __shared__ int   srcb[2*256];                  // byte offsets: src*1024

  const int tid  = threadIdx.x;
  const int wave = tid >> 6, lane = tid & 63;
  const int c = lane & 15, q = lane >> 4;
  const int fcol = wave*16 + c;
  const int nb0  = q*4;

  FU B[4][4];
  const uint4* Pw4 = (const uint4*)Pw;
  #pragma unroll
  for (int g = 0; g < 4; ++g)
    #pragma unroll
    for (int kt = 0; kt < 4; ++kt)
      B[g][kt].u4 = Pw4[((g*4 + kt)*128 + fcol)*4 + q];

  float bsum[4];
  #pragma unroll
  for (int g = 0; g < 4; ++g) bsum[g] = bih[g*HID + fcol] + bhh[g*HID + fcol];

  int aoff[4];
  #pragma unroll
  for (int kt = 0; kt < 4; ++kt)
    aoff[kt] = c*128 + (((kt*4 + q) ^ c) & 15)*8;

  const char* Gb = (const char*)Gu + fcol*8;

  for (int pair = blockIdx.x; pair < NPAIR; pair += gridDim.x) {
    const int c0 = pair*2;
    const bool has1 = (c0 + 1 < NCHUNK);
    const int c1 = has1 ? c0 + 1 : c0;
    if (tid < 256) {
      attb[tid] = atts[c0*256 + tid];
      srcb[tid] = srcs[c0*256 + tid] << 10;
    } else {
      attb[tid] = atts[c1*256 + (tid-256)];
      srcb[tid] = srcs[c1*256 + (tid-256)] << 10;
    }
    __syncthreads();

    float cst[2][4] = {{0.f,0.f,0.f,0.f},{0.f,0.f,0.f,0.f}};
    float hv [2][4] = {{0.f,0.f,0.f,0.f},{0.f,0.f,0.f,0.f}};
    uint2 pf[2][4];
    #pragma unroll
    for (int u = 0; u < 2; ++u)
      #pragma unroll
      for (int r = 0; r < 4; ++r)
        pf[u][r] = *(const uint2*)(Gb + srcb[u*256 + (nb0+r)*16]);

    #pragma unroll 2
    for (int t = 0; t < DEG; ++t) {
      uint2 cur[2][4]; float at[2][4];
      #pragma unroll
      for (int u = 0; u < 2; ++u)
        #pragma unroll
        for (int r = 0; r < 4; ++r) {
          cur[u][r] = pf[u][r];
          at[u][r]  = attb[u*256 + (nb0+r)*16 + t];
        }
      if (t < DEG-1) {
        #pragma unroll
        for (int u = 0; u < 2; ++u)
          #pragma unroll
          for (int r = 0; r < 4; ++r)
            pf[u][r] = *(const uint2*)(Gb + srcb[u*256 + (nb0+r)*16 + t+1]);
      }
      f32x4 acc[2][4];
      #pragma unroll
      for (int u = 0; u < 2; ++u)
        #pragma unroll
        for (int r = 0; r < 4; ++r) {
          acc[u][0][r] = bsum[0] + at[u][r]*bflo(cur[u][r].x);
          acc[u][1][r] = bsum[1] + at[u][r]*bfhi(cur[u][r].x);
          acc[u][2][r] = bsum[2] + at[u][r]*bflo(cur[u][r].y);
          acc[u][3][r] = bsum[3] + at[u][r]*bfhi(cur[u][r].y);
        }
      if (t > 0) {
        #pragma unroll
        for (int u = 0; u < 2; ++u) {
          const unsigned short* hb = hbuf[u][(t-1) & 1];
          FU A[4];
          #pragma unroll
          for (int kt = 0; kt < 4; ++kt) A[kt].u4 = *(const uint4*)(hb + aoff[kt]);
          #pragma unroll
          for (int g = 0; g < 4; ++g)
            #pragma unroll
            for (int kt = 0; kt < 4; ++kt)
              acc[u][g] = __builtin_amdgcn_mfma_f32_16x16x32_bf16(A[kt].bf, B[g][kt].bf, acc[u][g], 0, 0, 0);
        }
      }
      #pragma unroll
      for (int u = 0; u < 2; ++u)
        #pragma unroll
        for (int r = 0; r < 4; ++r) {
          const float ig = sigm (acc[u][0][r]);
          const float fg = sigm (acc[u][1][r]);
          const float gg = tanhx(acc[u][2][r]);
          const float og = sigm (acc[u][3][r]);
          cst[u][r] = fg*cst[u][r] + ig*gg;
          hv[u][r]  = og*tanhx(cst[u][r]);
        }
      if (t < DEG-1) {
        #pragma unroll
        for (int u = 0; u < 2; ++u) {
          unsigned short* hw = hbuf[u][t & 1];
          #pragma unroll
          for (int r = 0; r < 4; ++r) {
            const float other = __shfl_xor(hv[u][r], 1, 64);
            if ((c & 1) == 0) {
              const unsigned pack = (unsigned)f2bfu(hv[u][r]) | ((unsigned)f2bfu(other) << 16);
              const int node = nb0 + r;
              const int k = fcol;                           // even
              const int half = node*128 + (((k >> 3) ^ node) & 15)*8 + (k & 7);
              *(unsigned*)(hw + half) = pack;
            }
          }
        }
      }
      __syncthreads();
    }
    #pragma unroll
    for (int u = 0; u < 2; ++u) {
      if (u == 1 && !has1) break;
      const int nb = (u ? c1 : c0) * 16;
      #pragma unroll
      for (int r = 0; r < 4; ++r) {
        const int node = nb + nb0 + r;
        const float v = hv[u][r] + out[node*HID + fcol];
        out[node*HID + fcol] = (v > 0.f) ? v : 0.01f*v;
      }
    }
  }
}

// ---------------- launch ----------------
// ws layout (bytes):
//  gmax @0 (256) | xh @256 (25.6M) | xl @25600256 (25.6M)  [G aliases xh+xl]
//  projh @51200256 (12.8M) [scod aliases] | projl @64000256 (12.8M) [atts/srcs alias]
//  Wch @76800256  Wcl @76931328  wihh @77062400  wihl @77193472 (128K each)
//  vsrc @77324544 vtrg @77326592 (2K) | ssrc @77328640 strg @77728640 (400K each)
//  Pw @78128640 (128K)  -> end ~78.26 MB
extern "C" void kernel_launch(void* const* d_in, const int* in_sizes, int n_in,
                              void* d_out, int out_size, void* d_ws, size_t ws_size,
                              hipStream_t stream)
{
  (void)in_sizes; (void)n_in; (void)out_size; (void)ws_size;
  const float* x     = (const float*)d_in[0];
  const float* Wp    = (const float*)d_in[1];
  const float* a_src = (const float*)d_in[2];
  const float* a_trg = (const float*)d_in[3];
  const float* Ws    = (const float*)d_in[4];
  const float* bias  = (const float*)d_in[5];
  const float* wih_b = (const float*)d_in[10];
  const float* whh_b = (const float*)d_in[11];
  const float* bih_b = (const float*)d_in[12];
  const float* bhh_b = (const float*)d_in[13];
  const int*   eidx  = (const int*)d_in[14];
  const int* esrc = eidx;
  const int* etrg = eidx + NEDGE;
  float* out = (float*)d_out;

  unsigned char* ws = (unsigned char*)d_ws;
  unsigned int*   gmax = (unsigned int*)(ws + 0);
  unsigned short* xh   = (unsigned short*)(ws + 256);
  unsigned short* xl   = (unsigned short*)(ws + 25600256);
  unsigned short* Gh   = (unsigned short*)(ws + 256);          // aliases xh+xl
  unsigned short* projh= (unsigned short*)(ws + 51200256);
  unsigned short* projl= (unsigned short*)(ws + 64000256);
  double*         scod = (double*)(ws + 51200256);             // aliases projh
  float*          atts = (float*) (ws + 64000256);             // aliases projl
  int*            srcs = (int*)   (ws + 67200256);
  unsigned short* Wch  = (unsigned short*)(ws + 76800256);
  unsigned short* Wcl  = (unsigned short*)(ws + 76931328);
  unsigned short* wihh = (unsigned short*)(ws + 77062400);
  unsigned short* wihl = (unsigned short*)(ws + 77193472);
  double*         vsrc = (double*)(ws + 77324544);
  double*         vtrg = (double*)(ws + 77326592);
  double*         ssrc = (double*)(ws + 77328640);
  double*         strg = (double*)(ws + 77728640);
  unsigned short* Pw   = (unsigned short*)(ws + 78128640);

  k0_init<<<dim3(1), dim3(64), 0, stream>>>(gmax);
  k_cvt<<<dim3((N_NODES*FIN/4 + 255)/256), dim3(256), 0, stream>>>(x, xh, xl);
  k_w<<<dim3(769), dim3(256), 0, stream>>>(Wp, Ws, wih_b, whh_b, a_src, a_trg,
                                           Wch, Wcl, wihh, wihl, Pw, vsrc, vtrg);
  k_s<<<dim3((N_NODES+255)/256), dim3(256), 0, stream>>>(x, vsrc, vtrg, ssrc, strg);
  kgemm<FIN,0><<<dim3((N_NODES+127)/128, 4), dim3(256), 0, stream>>>(
      xh, xl, Wch, Wcl, bias, out, projh, projl);
  kgemm<HID,1><<<dim3((N_NODES+127)/128, 8), dim3(256), 0, stream>>>(
      projh, projl, wihh, wihl, bias, out, Gh, (unsigned short*)0);
  k3_scores<<<dim3((N_NODES+255)/256), dim3(256), 0, stream>>>(ssrc, strg, esrc, etrg, scod, gmax);
  k4_att<<<dim3((N_NODES+255)/256), dim3(256), 0, stream>>>(scod, esrc, gmax, atts, srcs);
  k5_lstm<<<dim3(256), dim3(512), 0, stream>>>(Gh, Pw, bih_b, bhh_b, atts, srcs, out);
}